// Round 2
// 409.661 us; speedup vs baseline: 1.0956x; 1.0956x over previous
//
#include <hip/hip_runtime.h>
#include <cstdint>
#include <cstddef>

// ---------------------------------------------------------------------------
// Cross_Self_attention: q=xWq+bq, k=xWk+bk, v=yWv+bv, P=softmax(qk^T),
// out = P @ (q*v).  B=8 S=2048 D=H=768, fp32 in/out, fp16 MFMA compute.
//
// RESUBMIT of round-1 design (round-1 bench died at the container level with
// no compile/correctness signal; pipeline ledger + addressing re-audited, no
// kernel-reachable hang/fault found -> treating as infra flake).
//
// scores GEMM and PV GEMM use a 256x256/BK64 8-wave deep-pipelined kernel
// (4 double-barrier phases, counted vmcnt, XOR-swizzled LDS, raw s_barrier).
// Projections/softmax unchanged from the 449us baseline.
// ---------------------------------------------------------------------------

#define BM 128
#define BN 128
#define BK 32

using half8 = __attribute__((ext_vector_type(8))) _Float16;  // MFMA A/B frag
using half4 = __attribute__((ext_vector_type(4))) _Float16;
using f32x4 = __attribute__((ext_vector_type(4))) float;     // 4 fp32 acc

// ---------------- fp32 -> fp16 bulk convert (x and y in one dispatch) ------
__global__ __launch_bounds__(256) void cvt2_f32_f16(
    const float* __restrict__ a, const float* __restrict__ b,
    _Float16* __restrict__ oa, _Float16* __restrict__ ob, int n4) {
  const float* in = blockIdx.y ? b : a;
  _Float16* out = blockIdx.y ? ob : oa;
  int i = blockIdx.x * 256 + threadIdx.x;
  if (i >= n4) return;
  float4 v = ((const float4*)in)[i];
  half4 o = {(_Float16)v.x, (_Float16)v.y, (_Float16)v.z, (_Float16)v.w};
  *(half4*)&out[(size_t)i * 4] = o;
}

// ---------------- all three W[768,768] -> W^T fp16 in one dispatch ---------
__global__ __launch_bounds__(256) void tr3_cvt768(
    const float* __restrict__ Wq, const float* __restrict__ Wk,
    const float* __restrict__ Wv, _Float16* __restrict__ Wt) {
  const float* W = (blockIdx.y == 0) ? Wq : (blockIdx.y == 1) ? Wk : Wv;
  _Float16* o = Wt + (size_t)blockIdx.y * 589824;
  int i = blockIdx.x * 256 + threadIdx.x;
  int h = i / 768, d = i - h * 768;
  o[i] = (_Float16)W[d * 768 + h];             // Wt[h][d] = W[d][h]
}

// ---------------- bt-form MFMA GEMM (projections only now) -----------------
// MODE 1: v=acc+bias[n]; g=v*qb[m,n]; gT[(b*768+n)*2048+s]=fp16(g)
// MODE 3: fused q|k proj: n<768 -> Cb=qb (bias), else Cb2=kb (bias2)
template <int MODE>
__global__ __launch_bounds__(256) void gemm_bt(
    const _Float16* __restrict__ Ab, int ldA, long sA,
    const _Float16* __restrict__ Bb, int ldB, long sB,
    void* __restrict__ Cb, int ldc, long sC,
    int K, const float* __restrict__ bias, const _Float16* __restrict__ qb,
    const float* __restrict__ bias2, void* __restrict__ Cb2) {
  __shared__ __align__(16) _Float16 lA[BM * BK];
  __shared__ __align__(16) _Float16 lB[BN * BK];

  const int tid  = threadIdx.x;
  const int lane = tid & 63;
  const int quad = lane >> 4;
  const int l15  = lane & 15;
  const int wave = tid >> 6;
  const int wm = (wave >> 1) * 64;
  const int wn = (wave & 1) * 64;
  const long bm = (long)blockIdx.x * BM;
  const long bn = (long)blockIdx.y * BN;
  const _Float16* A = Ab + (long)blockIdx.z * sA;
  const _Float16* B = Bb + (long)blockIdx.z * sB;

  f32x4 acc[4][4] = {};

  const int c0 = tid,        r0 = c0 >> 2, k0c = (c0 & 3) * 8;
  const int c1 = 256 + tid,  r1 = c1 >> 2, k1c = (c1 & 3) * 8;
  const _Float16* gA0 = A + (size_t)(bm + r0) * ldA + k0c;
  const _Float16* gA1 = A + (size_t)(bm + r1) * ldA + k1c;
  const _Float16* gB0 = B + (size_t)(bn + r0) * ldB + k0c;
  const _Float16* gB1 = B + (size_t)(bn + r1) * ldB + k1c;

  for (int kk = 0; kk < K; kk += BK) {
    __syncthreads();
    __builtin_amdgcn_global_load_lds(
        (const __attribute__((address_space(1))) void*)(gA0 + kk),
        (__attribute__((address_space(3))) void*)&lA[c0 * 8], 16, 0, 0);
    __builtin_amdgcn_global_load_lds(
        (const __attribute__((address_space(1))) void*)(gA1 + kk),
        (__attribute__((address_space(3))) void*)&lA[c1 * 8], 16, 0, 0);
    __builtin_amdgcn_global_load_lds(
        (const __attribute__((address_space(1))) void*)(gB0 + kk),
        (__attribute__((address_space(3))) void*)&lB[c0 * 8], 16, 0, 0);
    __builtin_amdgcn_global_load_lds(
        (const __attribute__((address_space(1))) void*)(gB1 + kk),
        (__attribute__((address_space(3))) void*)&lB[c1 * 8], 16, 0, 0);
    __syncthreads();

    half8 af[4], bfr[4];
#pragma unroll
    for (int i = 0; i < 4; i++) {
      af[i]  = *(const half8*)&lA[(wm + i * 16 + l15) * BK + quad * 8];
      bfr[i] = *(const half8*)&lB[(wn + i * 16 + l15) * BK + quad * 8];
    }
#pragma unroll
    for (int i = 0; i < 4; i++)
#pragma unroll
      for (int j = 0; j < 4; j++)
        acc[i][j] = __builtin_amdgcn_mfma_f32_16x16x32_f16(
            af[i], bfr[j], acc[i][j], 0, 0, 0);
  }

  if constexpr (MODE == 1) {
    __shared__ __align__(16) _Float16 xp[4 * 32 * 72];   // 18 KB
    _Float16* xw = &xp[wave * 2304];
    const long sbase = (bm & 2047) + wm;
    const long bb = bm >> 11;
    const long hbase = bn + wn;
#pragma unroll
    for (int jh = 0; jh < 2; jh++) {
      __syncthreads();
#pragma unroll
      for (int j2 = 0; j2 < 2; j2++) {
        const int j = jh * 2 + j2;
        const long n_g = hbase + j * 16 + l15;
        const float bsv = bias[n_g];
#pragma unroll
        for (int i = 0; i < 4; i++) {
          half4 pk;
#pragma unroll
          for (int r = 0; r < 4; r++) {
            long m_g = bm + wm + i * 16 + quad * 4 + r;
            float v = acc[i][j][r] + bsv;
            float q = (float)qb[m_g * (long)ldc + n_g];
            pk[r] = (_Float16)(v * q);
          }
          *(half4*)&xw[(j2 * 16 + l15) * 72 + i * 16 + quad * 4] = pk;
        }
      }
      __syncthreads();
#pragma unroll
      for (int t = 0; t < 4; t++) {
        const int n_r = t * 8 + (lane >> 3);
        const int m8 = (lane & 7) * 8;
        half8 vv = *(const half8*)&xw[n_r * 72 + m8];
        *(half8*)&((_Float16*)Cb)[(bb * 768 + hbase + 32 * jh + n_r) * 2048 +
                                  sbase + m8] = vv;
      }
    }
  } else {
#pragma unroll
    for (int i = 0; i < 4; i++) {
#pragma unroll
      for (int j = 0; j < 4; j++) {
#pragma unroll
        for (int r = 0; r < 4; r++) {
          long m = bm + wm + i * 16 + quad * 4 + r;
          long n = bn + wn + j * 16 + l15;
          float v = acc[i][j][r];
          if constexpr (MODE == 3) {
            const bool isq = (bn < 768);
            long nn = isq ? n : n - 768;
            v += (isq ? bias : bias2)[nn];
            _Float16* dst = (_Float16*)(isq ? Cb : Cb2);
            dst[m * ldc + nn] = (_Float16)v;
          } else {
            ((float*)Cb + (long)blockIdx.z * sC)[m * ldc + n] = v;
          }
        }
      }
    }
  }
}

// ---------------- 256x256 / BK64 / 8-wave deep-pipelined GEMM --------------
// A: [M][K] fp16 row-major (ldA, per-batch sA). B: bt-form [N][K] (ldB, sB).
// C: fp32 [M][N] (ldc, sC). K multiple of 64, NT=K/64 >= 3.
// LDS 128KB: [buf][op][half] of 128x64 halfs. Row-XOR swizzle (row&7)<<4
// applied on the GLOBAL source (linear LDS dest for global_load_lds) and on
// every ds_read address. 4 double-barrier phases per K-tile; per-phase
// half-tile staging schedule {Ah0(kt+1), Ah1(kt+1), Bh0(kt+2), Bh1(kt+2)};
// one counted s_waitcnt vmcnt(4) per K-tile at ph3 before the tile-boundary
// barrier (vmcnt(0) only at kt==NT-2). B-fragments register-cached at ph0,
// which legalizes staging B halves of kt+2 into the current buffer at
// ph2/ph3 of kt (>=2 barriers after the last read of that region).
__global__ __launch_bounds__(512, 2) void gemm256(
    const _Float16* __restrict__ Ab, int ldA, long sA,
    const _Float16* __restrict__ Bb, int ldB, long sB,
    float* __restrict__ Cb, int ldc, long sC, int K) {
  __shared__ __align__(16) _Float16 lds[8][8192];  // idx = buf*4+op*2+half

  const int tid  = threadIdx.x;
  const int lane = tid & 63;
  const int l15  = lane & 15;
  const int quad = lane >> 4;
  const int wave = tid >> 6;
  const int wmi  = wave >> 2;          // 0..1 : M wave index (128 rows each)
  const int wni  = wave & 3;           // 0..3 : N wave index (64 cols each)

  // XCD-chunked swizzle of within-batch block index (gridDim.x % 8 == 0)
  const int cpx = gridDim.x >> 3;
  const int l   = blockIdx.x;
  const int nl  = (l & 7) * cpx + (l >> 3);
  const long bm = (long)(nl & 7) * 256;
  const long bn = (long)(nl >> 3) * 256;

  const _Float16* A = Ab + (long)blockIdx.y * sA;
  const _Float16* B = Bb + (long)blockIdx.y * sB;
  float* C = Cb + (long)blockIdx.y * sC;

  // staging: thread covers chunk tid (row tid>>3) and 512+tid (row +64);
  // source k-offset pre-swizzled so linear LDS holds the XOR'd layout.
  const int srow = tid >> 3;
  const int scol = ((tid & 7) ^ (srow & 7)) * 8;
  const _Float16* gA = A + (bm + srow) * (long)ldA + scol;
  const _Float16* gB = B + (bn + srow) * (long)ldB + scol;

#define STAGE(op, GP, LD, buf, half, kt)                                       \
  { const _Float16* s0_ = (GP) + (long)(half) * 128 * (LD) + (long)(kt) * 64;  \
    _Float16* d0_ = &lds[(buf) * 4 + (op) * 2 + (half)][tid * 8];              \
    __builtin_amdgcn_global_load_lds(                                          \
        (const __attribute__((address_space(1))) void*)s0_,                    \
        (__attribute__((address_space(3))) void*)d0_, 16, 0, 0);               \
    __builtin_amdgcn_global_load_lds(                                          \
        (const __attribute__((address_space(1))) void*)(s0_ + 64 * (long)(LD)),\
        (__attribute__((address_space(3))) void*)(d0_ + 4096), 16, 0, 0); }

  const int NT = K >> 6;
  f32x4 acc[8][4] = {};

  // prologue queue: Bh0(0) Bh1(0) Ah0(0) Ah1(0) Bh0(1) Bh1(1)
  STAGE(1, gB, ldB, 0, 0, 0)
  STAGE(1, gB, ldB, 0, 1, 0)
  STAGE(0, gA, ldA, 0, 0, 0)
  STAGE(0, gA, ldA, 0, 1, 0)
  STAGE(1, gB, ldB, 1, 0, 1)
  STAGE(1, gB, ldB, 1, 1, 1)
  asm volatile("s_waitcnt vmcnt(4)" ::: "memory");   // kt0's 4 halves landed
  __builtin_amdgcn_s_barrier();
  asm volatile("" ::: "memory");

  const int sw4 = (l15 & 7) << 4;      // byte XOR mask for ds_read
  const int rB0 = (wni & 1) * 64;      // row base inside B half
  half8 bf[4][2];                      // B frags cached per K-tile

  for (int kt = 0; kt < NT; ++kt) {
    const int b = kt & 1;
    const char* lA = (const char*)lds[b * 4 + wmi];
    const char* lB = (const char*)lds[b * 4 + 2 + (wni >> 1)];
#pragma unroll
    for (int ph = 0; ph < 4; ++ph) {
      half8 af[2][2];
#pragma unroll
      for (int i2 = 0; i2 < 2; ++i2)
#pragma unroll
        for (int ks = 0; ks < 2; ++ks)
          af[i2][ks] = *(const half8*)(lA + (((ph * 2 + i2) * 16 + l15) * 128 +
                                             ((((ks << 2) | quad) << 4) ^ sw4)));
      if (ph == 0) {
#pragma unroll
        for (int j = 0; j < 4; ++j)
#pragma unroll
          for (int ks = 0; ks < 2; ++ks)
            bf[j][ks] = *(const half8*)(lB + ((rB0 + j * 16 + l15) * 128 +
                                              ((((ks << 2) | quad) << 4) ^ sw4)));
      }
      if (ph == 0 && kt + 1 < NT) STAGE(0, gA, ldA, b ^ 1, 0, kt + 1)
      if (ph == 1 && kt + 1 < NT) STAGE(0, gA, ldA, b ^ 1, 1, kt + 1)
      if (ph == 2 && kt + 2 < NT) STAGE(1, gB, ldB, b, 0, kt + 2)
      if (ph == 3 && kt + 2 < NT) STAGE(1, gB, ldB, b, 1, kt + 2)
      asm volatile("" ::: "memory");
      __builtin_amdgcn_s_barrier();
      asm volatile("" ::: "memory");
      __builtin_amdgcn_s_setprio(1);
#pragma unroll
      for (int i2 = 0; i2 < 2; ++i2)
#pragma unroll
        for (int j = 0; j < 4; ++j)
#pragma unroll
          for (int ks = 0; ks < 2; ++ks)
            acc[ph * 2 + i2][j] = __builtin_amdgcn_mfma_f32_16x16x32_f16(
                af[i2][ks], bf[j][ks], acc[ph * 2 + i2][j], 0, 0, 0);
      __builtin_amdgcn_s_setprio(0);
      if (ph == 3) {
        if (kt < NT - 2) {
          asm volatile("s_waitcnt vmcnt(4)" ::: "memory");  // kt+1 landed
        } else if (kt == NT - 2) {
          asm volatile("s_waitcnt vmcnt(0)" ::: "memory");  // final drain
        }
      }
      asm volatile("" ::: "memory");
      __builtin_amdgcn_s_barrier();
      asm volatile("" ::: "memory");
    }
  }
#undef STAGE

  // epilogue: D layout col=lane&15, row=quad*4+reg
  float* Cp = C + (bm + wmi * 128 + quad * 4) * (long)ldc + bn + wni * 64 + l15;
#pragma unroll
  for (int i = 0; i < 8; ++i)
#pragma unroll
    for (int j = 0; j < 4; ++j)
#pragma unroll
      for (int r = 0; r < 4; ++r)
        Cp[(i * 16 + r) * (long)ldc + j * 16] = acc[i][j][r];
}

// ---------------- row softmax: fp32 scores[row,2048] -> fp16 probs ---------
__global__ __launch_bounds__(256) void softmax_rows(
    const float* __restrict__ sc, _Float16* __restrict__ pr, int prPitch) {
  const int row = blockIdx.x;
  const float* x = sc + (size_t)row * 2048;
  const int t = threadIdx.x;
  float4 v0 = ((const float4*)x)[2 * t];
  float4 v1 = ((const float4*)x)[2 * t + 1];
  float e[8] = {v0.x, v0.y, v0.z, v0.w, v1.x, v1.y, v1.z, v1.w};

  float m = e[0];
#pragma unroll
  for (int i = 1; i < 8; i++) m = fmaxf(m, e[i]);
#pragma unroll
  for (int o = 32; o; o >>= 1) m = fmaxf(m, __shfl_xor(m, o, 64));
  __shared__ float red[4];
  if ((t & 63) == 0) red[t >> 6] = m;
  __syncthreads();
  m = fmaxf(fmaxf(red[0], red[1]), fmaxf(red[2], red[3]));

  float s = 0.f;
#pragma unroll
  for (int i = 0; i < 8; i++) { e[i] = __expf(e[i] - m); s += e[i]; }
#pragma unroll
  for (int o = 32; o; o >>= 1) s += __shfl_xor(s, o, 64);
  __syncthreads();
  if ((t & 63) == 0) red[t >> 6] = s;
  __syncthreads();
  s = red[0] + red[1] + red[2] + red[3];
  float inv = 1.0f / s;

  union { _Float16 h[8]; uint4 v; } o;
#pragma unroll
  for (int i = 0; i < 8; i++) o.h[i] = (_Float16)(e[i] * inv);
  ((uint4*)(pr + (size_t)row * prPitch))[t] = o.v;
}

// ---------------------------------------------------------------------------
extern "C" void kernel_launch(void* const* d_in, const int* in_sizes, int n_in,
                              void* d_out, int out_size, void* d_ws, size_t ws_size,
                              hipStream_t stream) {
  const float* x  = (const float*)d_in[0];
  const float* y  = (const float*)d_in[1];
  const float* Wq = (const float*)d_in[2];
  const float* bq = (const float*)d_in[3];
  const float* Wk = (const float*)d_in[4];
  const float* bk = (const float*)d_in[5];
  const float* Wv = (const float*)d_in[6];
  const float* bv = (const float*)d_in[7];
  float* out = (float*)d_out;

  const int S = 2048, D = 768, H = 768;
  const long SH = (long)S * H;          // 1572864
  char* ws = (char*)d_ws;
  _Float16* qb  = (_Float16*)(ws + 0);
  _Float16* kb  = (_Float16*)(ws + 25165824);
  _Float16* gT  = (_Float16*)(ws + 50331648);
  _Float16* xb  = (_Float16*)(ws + 75497472);
  _Float16* yb  = (_Float16*)(ws + 100663296);
  _Float16* WtQ = (_Float16*)(ws + 125829120);
  _Float16* WtV = WtQ + 2 * 589824;
  float* scores = (float*)(ws + 75497472);

  // 1) prep
  cvt2_f32_f16<<<dim3(12288, 2), 256, 0, stream>>>(x, y, xb, yb, 3145728);
  tr3_cvt768<<<dim3(2304, 3), 256, 0, stream>>>(Wq, Wk, Wv, WtQ);

  // 2) projections (old 128-tile kernel)
  gemm_bt<3><<<dim3(128, 12, 1), 256, 0, stream>>>(
      xb, D, 0, WtQ, D, 0, qb, H, 0, D, bq, nullptr, bk, kb);
  gemm_bt<1><<<dim3(128, 6, 1), 256, 0, stream>>>(
      yb, D, 0, WtV, D, 0, gT, H, 0, D, bv, qb, nullptr, nullptr);

  // 3) attention: 256-tile deep-pipelined GEMMs. probs in-place fp16,
  // pitch 4096 halfs in the first 4KB of each 8KB score row.
  _Float16* probs = (_Float16*)scores;
  if (ws_size >= 209715200ull) {        // Tier A: all 8 batches
    gemm256<<<dim3(64, 8), 512, 0, stream>>>(
        qb, H, SH, kb, H, SH, scores, S, (long)S * S, D);
    softmax_rows<<<16384, 256, 0, stream>>>(scores, probs, 4096);
    gemm256<<<dim3(24, 8), 512, 0, stream>>>(
        probs, 4096, (long)S * 4096, gT, S, SH, out, H, SH, S);
  } else {                              // Tier C: 4 rounds x 2 batches
    for (int r = 0; r < 4; r++) {
      const long b0 = 2 * r;
      gemm256<<<dim3(64, 2), 512, 0, stream>>>(
          qb + b0 * SH, H, SH, kb + b0 * SH, H, SH, scores, S, (long)S * S, D);
      softmax_rows<<<4096, 256, 0, stream>>>(scores, probs, 4096);
      gemm256<<<dim3(24, 2), 512, 0, stream>>>(
          probs, 4096, (long)S * 4096, gT + b0 * SH, S, SH,
          out + b0 * SH, H, SH, S);
    }
  }
}